// Round 1
// baseline (200.016 us; speedup 1.0000x reference)
//
#include <hip/hip_runtime.h>

#define NH 8
#define DQ 32
#define DV 32
#define LQ 384
#define LK 384
#define BS 2

// ---------------- Kernel 1: precompute qW and kW^T (+b1) into ws ----------------
// ws layout: qW [BS*NH][LQ][64]  (393216 floats), then kT [BS*NH][64][LK] (393216 floats)
__global__ __launch_bounds__(256) void precompute_kernel(
    const float* __restrict__ qin, const float* __restrict__ kin,
    const float* __restrict__ w1, const float* __restrict__ b1,
    float* __restrict__ ws)
{
    const int NQ = BS * NH * LQ * 64; // 393216
    int gid = blockIdx.x * 256 + threadIdx.x;
    if (gid < NQ) {
        // qW[bh][q][e] : lanes vary e -> coalesced write, w1 coalesced, q broadcast
        int e  = gid & 63;
        int qe = gid >> 6;
        int qq = qe % LQ;
        int bh = qe / LQ;
        int b = bh >> 3, h = bh & 7;
        const float* qrow = qin + ((size_t)(b * LQ + qq)) * (NH * DQ) + h * DQ;
        const float* w1c  = w1 + (size_t)(h * 64) * 64 + e;
        float acc = 0.f;
        #pragma unroll
        for (int d = 0; d < 32; ++d)
            acc += qrow[d] * w1c[d * 64];
        ws[gid] = acc;
    } else {
        // kT[bh][e][k] : lanes vary k -> coalesced write; k reads gather (L1-resident)
        int gid2 = gid - NQ;
        int k   = gid2 % LK;
        int ebh = gid2 / LK;
        int e  = ebh & 63;
        int bh = ebh >> 6;
        int b = bh >> 3, h = bh & 7;
        const float* krow = kin + ((size_t)(b * LK + k)) * (NH * DQ) + h * DQ;
        const float* w1c  = w1 + (size_t)(h * 64 + 32) * 64 + e;
        float acc = b1[h * 64 + e];
        #pragma unroll
        for (int d = 0; d < 32; ++d)
            acc += krow[d] * w1c[d * 64];
        ws[NQ + gid2] = acc;
    }
}

// tanh(x) = 1 - 2/(1+exp(2x));  exp(+inf)->1, exp(0)->-1 handled correctly.
__device__ __forceinline__ float tanh_fast(float x) {
    float E = __expf(x + x);
    float r = __builtin_amdgcn_rcpf(E + 1.0f);
    return __builtin_fmaf(-2.0f, r, 1.0f);
}

// ---------------- Kernel 2: scores + softmax + att write + PV ----------------
// grid = 512 blocks: bh = blockIdx.x>>5 (16), tile = blockIdx.x&31 (32), 12 q-rows/block
__global__ __launch_bounds__(256) void attn_kernel(
    const float* __restrict__ vin,
    const int* __restrict__ qlens, const int* __restrict__ klens,
    const float* __restrict__ w2g,
    const float* __restrict__ ws,
    float* __restrict__ outg, float* __restrict__ attg)
{
    __shared__ __align__(16) float smem[64 * 192];   // 48KB: kT chunk, later V[384][32]
    __shared__ __align__(16) float qWs[12 * 64];     // 3KB
    __shared__ __align__(16) float att_s[4][LK];     // 6KB
    __shared__ __align__(16) float w2s[64];

    const int tid  = threadIdx.x;
    const int wave = tid >> 6, lane = tid & 63;
    const int bh   = blockIdx.x >> 5, tile = blockIdx.x & 31;
    const int b = bh >> 3, h = bh & 7;
    const int q0 = tile * 12;
    const int klen = klens[b];
    const int qlen = qlens[b];

    const float*  qWg  = ws + ((size_t)bh * LQ + q0) * 64;
    const float4* kTg4 = (const float4*)(ws + (size_t)BS * NH * LQ * 64) + (size_t)bh * 64 * 96;

    // stage qW rows (768 floats = 192 f4) and w2 (16 f4)
    if (tid < 192) ((float4*)qWs)[tid] = ((const float4*)qWg)[tid];
    else if (tid < 208) ((float4*)w2s)[tid - 192] = ((const float4*)(w2g + h * 64))[tid - 192];

    float sc[3][6];
    #pragma unroll
    for (int i = 0; i < 3; ++i)
        #pragma unroll
        for (int j = 0; j < 6; ++j) sc[i][j] = 0.f;

    // two k-chunks of 192; sc[i][c*3+jj] corresponds to k = (c*3+jj)*64 + lane
    for (int c = 0; c < 2; ++c) {
        __syncthreads();
        #pragma unroll
        for (int i = 0; i < 12; ++i) {
            int fidx = tid + i * 256;
            int e  = fidx / 48;           // 48 float4 per e-row in LDS
            int k4 = fidx - e * 48;
            ((float4*)smem)[fidx] = kTg4[e * 96 + c * 48 + k4];
        }
        __syncthreads();
        #pragma unroll
        for (int i = 0; i < 3; ++i) {
            int lr = wave * 3 + i;
            const float4* qv4 = (const float4*)&qWs[lr * 64];
            const float4* w24 = (const float4*)w2s;
            float a0 = 0.f, a1 = 0.f, a2 = 0.f;
            #pragma unroll
            for (int e4 = 0; e4 < 16; ++e4) {
                float4 qv = qv4[e4];
                float4 wv = w24[e4];
                float qvv[4] = {qv.x, qv.y, qv.z, qv.w};
                float wvv[4] = {wv.x, wv.y, wv.z, wv.w};
                #pragma unroll
                for (int u = 0; u < 4; ++u) {
                    const float* kb = &smem[(e4 * 4 + u) * 192 + lane];
                    float t0 = tanh_fast(qvv[u] + kb[0]);
                    float t1 = tanh_fast(qvv[u] + kb[64]);
                    float t2 = tanh_fast(qvv[u] + kb[128]);
                    a0 = __builtin_fmaf(wvv[u], t0, a0);
                    a1 = __builtin_fmaf(wvv[u], t1, a1);
                    a2 = __builtin_fmaf(wvv[u], t2, a2);
                }
            }
            sc[i][c * 3 + 0] += a0;
            sc[i][c * 3 + 1] += a1;
            sc[i][c * 3 + 2] += a2;
        }
    }

    // stage V (reuses smem arena): Vs[k][dv], 384*32 floats
    __syncthreads();
    {
        const float4* vg = (const float4*)(vin + (size_t)b * LK * (NH * DV) + h * DV);
        #pragma unroll
        for (int i = 0; i < 12; ++i) {
            int fidx = tid + i * 256;
            int k = fidx >> 3, dv4 = fidx & 7;
            ((float4*)smem)[fidx] = vg[(size_t)k * 64 + dv4];
        }
    }
    __syncthreads();

    const int dv = lane & 31, half = lane >> 5;

    #pragma unroll 1
    for (int i = 0; i < 3; ++i) {
        int lr = wave * 3 + i;
        int q  = q0 + lr;

        // masked softmax over k (k = j*64 + lane)
        float p[6];
        float m = -1e9f;
        #pragma unroll
        for (int j = 0; j < 6; ++j) {
            int kk = j * 64 + lane;
            float svj = (kk < klen) ? sc[i][j] : -1e9f;
            m = fmaxf(m, svj);
        }
        #pragma unroll
        for (int off = 32; off >= 1; off >>= 1) m = fmaxf(m, __shfl_xor(m, off));
        float s = 0.f;
        #pragma unroll
        for (int j = 0; j < 6; ++j) {
            int kk = j * 64 + lane;
            p[j] = (kk < klen) ? __expf(sc[i][j] - m) : 0.f;
            s += p[j];
        }
        #pragma unroll
        for (int off = 32; off >= 1; off >>= 1) s += __shfl_xor(s, off);
        float inv = __builtin_amdgcn_rcpf(s);

        float* arow = att_s[wave];
        float* ag   = attg + ((size_t)bh * LQ + q) * LK;
        #pragma unroll
        for (int j = 0; j < 6; ++j) {
            float a = p[j] * inv;
            arow[j * 64 + lane] = a;
            ag[j * 64 + lane]   = a;
        }

        // PV: half-wave over k, dv = lane&31
        const float* ar = arow + half * 192;
        const float* vb = smem + (size_t)half * 192 * 32 + dv;
        float acc = 0.f;
        #pragma unroll
        for (int kk = 0; kk < 192; kk += 4) {
            float4 a4 = *(const float4*)(ar + kk);
            acc += a4.x * vb[(kk + 0) * 32];
            acc += a4.y * vb[(kk + 1) * 32];
            acc += a4.z * vb[(kk + 2) * 32];
            acc += a4.w * vb[(kk + 3) * 32];
        }
        acc += __shfl_xor(acc, 32);
        if (lane < 32) {
            outg[((size_t)(b * LQ + q)) * (NH * DV) + h * DV + dv] = (q < qlen) ? acc : 0.f;
        }
    }
}

extern "C" void kernel_launch(void* const* d_in, const int* in_sizes, int n_in,
                              void* d_out, int out_size, void* d_ws, size_t ws_size,
                              hipStream_t stream) {
    const float* q    = (const float*)d_in[0];
    const float* k    = (const float*)d_in[1];
    const float* v    = (const float*)d_in[2];
    const int*   qlen = (const int*)d_in[3];
    const int*   klen = (const int*)d_in[4];
    const float* w1   = (const float*)d_in[5];
    const float* b1   = (const float*)d_in[6];
    const float* w2   = (const float*)d_in[7];
    float* out = (float*)d_out;
    float* att = out + (size_t)BS * LQ * NH * DV;   // out: 196608 floats, att: 2359296 floats
    float* ws  = (float*)d_ws;                      // needs 786432 floats = 3 MB

    precompute_kernel<<<3072, 256, 0, stream>>>(q, k, w1, b1, ws);
    attn_kernel<<<512, 256, 0, stream>>>(v, qlen, klen, w2, ws, out, att);
}

// Round 2
// 113.462 us; speedup vs baseline: 1.7628x; 1.7628x over previous
//
#include <hip/hip_runtime.h>

#define NH 8
#define LQ 384
#define LK 384
#define BS 2
#define NQE (BS*NH*LQ*64)   // 393216: size of Eq table

// ---------------- Kernel 1: Eq = exp(2*qW), Ek = exp(2*(kW+b1)) ----------------
// ws layout: Eq [BS*NH][LQ][64], then Ek [BS*NH][64][LK] (e-major, k contiguous)
__global__ __launch_bounds__(256) void precompute_kernel(
    const float* __restrict__ qin, const float* __restrict__ kin,
    const float* __restrict__ w1, const float* __restrict__ b1,
    float* __restrict__ ws)
{
    __shared__ float tile[64][65];   // used only by part B; pad 65 -> conflict-free transpose
    if (blockIdx.x < 1536) {
        // part A: Eq, fully coalesced (lanes vary e, q-row broadcast)
        int gid = blockIdx.x * 256 + threadIdx.x;
        int e  = gid & 63;
        int qe = gid >> 6;
        int qq = qe % LQ;
        int bh = qe / LQ;
        int b = bh >> 3, h = bh & 7;
        const float* qrow = qin + ((size_t)(b * LQ + qq)) * (NH * 32) + h * 32;
        const float* w1c  = w1 + (size_t)(h * 64) * 64 + e;
        float acc = 0.f;
        #pragma unroll
        for (int d = 0; d < 32; ++d)
            acc = __builtin_fmaf(qrow[d], w1c[d * 64], acc);
        ws[gid] = __expf(acc + acc);
    } else {
        // part B: Ek computed coalesced (lanes vary e), transposed via LDS,
        // written out [e][k] with coalesced 256B rows.
        int bid = blockIdx.x - 1536;          // 0..95
        int bh = bid / 6, kt = bid % 6;
        int b = bh >> 3, h = bh & 7;
        int k0 = kt * 64;
        int lane = threadIdx.x & 63, w = threadIdx.x >> 6;
        float w1c[32];
        const float* w1p = w1 + (size_t)(h * 64 + 32) * 64 + lane;
        #pragma unroll
        for (int d = 0; d < 32; ++d) w1c[d] = w1p[d * 64];
        float bv = b1[h * 64 + lane];
        for (int s = 0; s < 16; ++s) {
            int krel = w * 16 + s;
            const float* krow = kin + ((size_t)(b * LK + k0 + krel)) * (NH * 32) + h * 32;
            float acc = bv;
            #pragma unroll
            for (int d = 0; d < 32; ++d)
                acc = __builtin_fmaf(krow[d], w1c[d], acc);
            tile[krel][lane] = __expf(acc + acc);
        }
        __syncthreads();
        float* wk = ws + NQE + (size_t)bh * 64 * LK + k0;
        for (int s = 0; s < 16; ++s) {
            int e = w * 16 + s;
            wk[(size_t)e * LK + lane] = tile[lane][e];   // bank (lane+e)%32: 2-way, free
        }
    }
}

// ---------------- Kernel 2: scores (rcp form) + softmax + att + PV ----------------
// grid = 768: bh = blockIdx.x/48, q-tile of 8 rows; 4 waves, 2 q-rows per wave.
__global__ __launch_bounds__(256, 4) void attn_kernel(
    const float* __restrict__ vin,
    const int* __restrict__ qlens, const int* __restrict__ klens,
    const float* __restrict__ w2g, const float* __restrict__ ws,
    float* __restrict__ outg, float* __restrict__ attg)
{
    __shared__ __align__(16) float ek[16 * LK];      // 24KB: Ek e-chunk, later V half [192][32]
    __shared__ __align__(16) float att_s[8][LK];     // 12KB
    __shared__ __align__(16) float eqs[8 * 64];      // 2KB
    __shared__ __align__(16) float w2s[64];

    const int tid = threadIdx.x, wave = tid >> 6, lane = tid & 63;
    const int bh = blockIdx.x / 48, tile = blockIdx.x % 48;
    const int b = bh >> 3, h = bh & 7;
    const int q0 = tile * 8;
    const int klen = klens[b], qlen = qlens[b];

    // stage Eq rows (8*64 floats = 128 f4) and w2 (16 f4)
    if (tid < 128) ((float4*)eqs)[tid] = ((const float4*)(ws + ((size_t)bh * LQ + q0) * 64))[tid];
    else if (tid < 144) ((float4*)w2s)[tid - 128] = ((const float4*)(w2g + h * 64))[tid - 128];

    float sc[2][6];
    #pragma unroll
    for (int i = 0; i < 2; ++i)
        #pragma unroll
        for (int j = 0; j < 6; ++j) sc[i][j] = 0.f;

    const float* ekg = ws + NQE + (size_t)bh * 64 * LK;
    for (int ec = 0; ec < 4; ++ec) {
        __syncthreads();
        const float4* src = (const float4*)(ekg + (size_t)ec * 16 * LK);
        #pragma unroll
        for (int r = 0; r < 6; ++r)
            ((float4*)ek)[tid + r * 256] = src[tid + r * 256];
        __syncthreads();
        #pragma unroll 2
        for (int e = 0; e < 16; ++e) {
            float kv[6];
            #pragma unroll
            for (int j = 0; j < 6; ++j) kv[j] = ek[e * LK + j * 64 + lane];
            float wv = w2s[ec * 16 + e];
            #pragma unroll
            for (int i = 0; i < 2; ++i) {
                float qv = eqs[(wave * 2 + i) * 64 + ec * 16 + e];
                #pragma unroll
                for (int j = 0; j < 6; ++j) {
                    float E = qv * kv[j];
                    float r = __builtin_amdgcn_rcpf(1.0f + E);
                    sc[i][j] = __builtin_fmaf(wv, r, sc[i][j]);
                }
            }
        }
    }

    // softmax over k (score_eff = -2*acc; shift-invariant so Sum(w2) dropped)
    #pragma unroll
    for (int i = 0; i < 2; ++i) {
        int row = wave * 2 + i, q = q0 + row;
        float s_[6], p[6];
        float m = -3.4e38f;
        #pragma unroll
        for (int j = 0; j < 6; ++j) {
            int kk = j * 64 + lane;
            float v = -2.0f * sc[i][j];
            s_[j] = (kk < klen) ? v : -3.4e38f;
            m = fmaxf(m, s_[j]);
        }
        #pragma unroll
        for (int off = 32; off >= 1; off >>= 1) m = fmaxf(m, __shfl_xor(m, off));
        float ssum = 0.f;
        #pragma unroll
        for (int j = 0; j < 6; ++j) {
            int kk = j * 64 + lane;
            p[j] = (kk < klen) ? __expf(s_[j] - m) : 0.f;
            ssum += p[j];
        }
        #pragma unroll
        for (int off = 32; off >= 1; off >>= 1) ssum += __shfl_xor(ssum, off);
        float inv = __builtin_amdgcn_rcpf(ssum);
        float* arow = att_s[row];
        float* ag = attg + ((size_t)(bh * LQ + q)) * LK;
        #pragma unroll
        for (int j = 0; j < 6; ++j) {
            float a = p[j] * inv;
            arow[j * 64 + lane] = a;
            ag[j * 64 + lane]   = a;
        }
    }

    // PV: V staged in two 192-row halves into the ek arena
    const int dv = lane & 31, halfk = lane >> 5;
    float oacc[2] = {0.f, 0.f};
    for (int c = 0; c < 2; ++c) {
        __syncthreads();   // all waves done with ek (and prior V half) before overwrite
        const float4* vg = (const float4*)(vin + ((size_t)(b * LK + c * 192)) * (NH * 32) + h * 32);
        #pragma unroll
        for (int r = 0; r < 6; ++r) {
            int fidx = tid + r * 256;
            int kk = fidx >> 3, d4 = fidx & 7;
            ((float4*)ek)[fidx] = vg[(size_t)kk * 64 + d4];
        }
        __syncthreads();
        #pragma unroll
        for (int i = 0; i < 2; ++i) {
            const float* ar = att_s[wave * 2 + i] + c * 192 + halfk * 96;
            const float* vb = ek + (halfk * 96) * 32 + dv;
            float acc = 0.f;
            #pragma unroll
            for (int kk = 0; kk < 96; kk += 4) {
                float4 a4 = *(const float4*)(ar + kk);
                acc = __builtin_fmaf(a4.x, vb[(kk + 0) * 32], acc);
                acc = __builtin_fmaf(a4.y, vb[(kk + 1) * 32], acc);
                acc = __builtin_fmaf(a4.z, vb[(kk + 2) * 32], acc);
                acc = __builtin_fmaf(a4.w, vb[(kk + 3) * 32], acc);
            }
            oacc[i] += acc;
        }
    }
    #pragma unroll
    for (int i = 0; i < 2; ++i) oacc[i] += __shfl_xor(oacc[i], 32);
    if (lane < 32) {
        #pragma unroll
        for (int i = 0; i < 2; ++i) {
            int q = q0 + wave * 2 + i;
            outg[((size_t)(b * LQ + q)) * (NH * 32) + h * 32 + dv] = (q < qlen) ? oacc[i] : 0.f;
        }
    }
}

extern "C" void kernel_launch(void* const* d_in, const int* in_sizes, int n_in,
                              void* d_out, int out_size, void* d_ws, size_t ws_size,
                              hipStream_t stream) {
    const float* q    = (const float*)d_in[0];
    const float* k    = (const float*)d_in[1];
    const float* v    = (const float*)d_in[2];
    const int*   qlen = (const int*)d_in[3];
    const int*   klen = (const int*)d_in[4];
    const float* w1   = (const float*)d_in[5];
    const float* b1   = (const float*)d_in[6];
    const float* w2   = (const float*)d_in[7];
    float* out = (float*)d_out;
    float* att = out + (size_t)BS * LQ * NH * 32;   // out: 196608, att: 2359296 floats
    float* ws  = (float*)d_ws;                      // 786432 floats = 3 MB

    precompute_kernel<<<1632, 256, 0, stream>>>(q, k, w1, b1, ws);
    attn_kernel<<<768, 256, 0, stream>>>(v, qlen, klen, w2, ws, out, att);
}